// Round 8
// baseline (122.835 us; speedup 1.0000x reference)
//
#include <hip/hip_runtime.h>
#include <math.h>

typedef float f4 __attribute__((ext_vector_type(4)));

#define BDIM 256
#define TROWS 8                  // rows per tile: 8*1200B = 9600B ≡ 0 (mod 128)
#define TILE_F4_IN 600           // per-tensor f4 per tile
#define TILE_F4_OUT 1200         // out f4 per tile
#define NBLK 1024                // persistent blocks (4/CU)

__device__ __forceinline__ float dot4(f4 a, f4 w) {
    return a[0]*w[0] + a[1]*w[1] + a[2]*w[2] + a[3]*w[3];
}

__global__ __launch_bounds__(BDIM, 4) void taskselector_kernel(
    const f4* __restrict__ se1,
    const f4* __restrict__ se2,
    const float* __restrict__ W,
    const float* __restrict__ bvec,
    const f4* __restrict__ u4,
    f4* __restrict__ out,
    int ntiles)
{
    __shared__ f4 L1[2][TILE_F4_IN];     // 19200 B
    __shared__ f4 L2[2][TILE_F4_IN];     // 19200 B
    __shared__ float SEL[2][TROWS * 2];  // 128 B
    __shared__ f4 UL[2][TROWS / 2];      // 128 B

    const int tid  = threadIdx.x;
    const int lane = tid & 63;
    const int wave = tid >> 6;
    const bool t3  = (tid < TILE_F4_IN - 2 * BDIM);   // 88 threads
    const f4 zero = (f4)0.f;

    // ---- W / b into regs once per (persistent) block ----
    const bool extra = (lane < 11);
    const f4* W0 = (const f4*)W;
    const f4* W1 = (const f4*)(W + 600);
    f4 w0a = W0[lane];
    f4 w0b = extra ? W0[64 + lane]  : zero;
    f4 w0c = W0[75 + lane];
    f4 w0d = extra ? W0[139 + lane] : zero;
    f4 w1a = W1[lane];
    f4 w1b = extra ? W1[64 + lane]  : zero;
    f4 w1c = W1[75 + lane];
    f4 w1d = extra ? W1[139 + lane] : zero;
    const float b0 = bvec[0];
    const float b1 = bvec[1];

    const int nit = ntiles / NBLK;       // 16 for this problem (exact)

    // ---- prologue: preload tile 0 into registers ----
    int tile = blockIdx.x;
    f4 rt0, rt1, rt2, rq0, rq1, rq2, ru;
    {
        const f4* s1 = se1 + (size_t)tile * TILE_F4_IN;
        const f4* s2 = se2 + (size_t)tile * TILE_F4_IN;
        rt0 = __builtin_nontemporal_load(s1 + tid);
        rt1 = __builtin_nontemporal_load(s1 + BDIM + tid);
        rt2 = t3 ? __builtin_nontemporal_load(s1 + 2 * BDIM + tid) : zero;
        rq0 = __builtin_nontemporal_load(s2 + tid);
        rq1 = __builtin_nontemporal_load(s2 + BDIM + tid);
        rq2 = t3 ? __builtin_nontemporal_load(s2 + 2 * BDIM + tid) : zero;
        ru  = (tid < TROWS / 2) ? u4[(size_t)tile * (TROWS / 2) + tid] : zero;
    }

    for (int it = 0; it < nit; ++it) {
        const int cur = it & 1;

        // ---- stage current tile regs -> LDS[cur] ----
        L1[cur][tid] = rt0;
        L1[cur][BDIM + tid] = rt1;
        L2[cur][tid] = rq0;
        L2[cur][BDIM + tid] = rq1;
        if (t3) {
            L1[cur][2 * BDIM + tid] = rt2;
            L2[cur][2 * BDIM + tid] = rq2;
        }
        if (tid < TROWS / 2) UL[cur][tid] = ru;
        __syncthreads();

        // ---- issue next tile's loads (latency hides under compute+store) ----
        if (it + 1 < nit) {
            const int ntile = tile + NBLK;
            const f4* s1 = se1 + (size_t)ntile * TILE_F4_IN;
            const f4* s2 = se2 + (size_t)ntile * TILE_F4_IN;
            rt0 = __builtin_nontemporal_load(s1 + tid);
            rt1 = __builtin_nontemporal_load(s1 + BDIM + tid);
            if (t3) rt2 = __builtin_nontemporal_load(s1 + 2 * BDIM + tid);
            rq0 = __builtin_nontemporal_load(s2 + tid);
            rq1 = __builtin_nontemporal_load(s2 + BDIM + tid);
            if (t3) rq2 = __builtin_nontemporal_load(s2 + 2 * BDIM + tid);
            if (tid < TROWS / 2) ru = u4[(size_t)ntile * (TROWS / 2) + tid];
        }

        // ---- compute selectors: wave w -> rows {2w, 2w+1} ----
        const float* ULf = (const float*)&UL[cur][0];
        #pragma unroll
        for (int rr = 0; rr < 2; rr++) {
            const int r = wave * 2 + rr;
            const f4* R1 = &L1[cur][0] + r * 75;
            const f4* R2 = &L2[cur][0] + r * 75;
            f4 a0 = R1[lane];
            f4 c0 = R2[lane];
            f4 a1 = extra ? R1[64 + lane] : zero;
            f4 c1 = extra ? R2[64 + lane] : zero;
            float d0 = dot4(a0, w0a) + dot4(a1, w0b) + dot4(c0, w0c) + dot4(c1, w0d);
            float d1 = dot4(a0, w1a) + dot4(a1, w1b) + dot4(c0, w1c) + dot4(c1, w1d);
            #pragma unroll
            for (int off = 32; off > 0; off >>= 1) {
                d0 += __shfl_xor(d0, off, 64);
                d1 += __shfl_xor(d1, off, 64);
            }
            // epilogue — identical formula to the proven (absmax 0.0) version
            float z0 = fmaxf(d0 + b0, 0.f);
            float z1 = fmaxf(d1 + b1, 0.f);
            float m  = fmaxf(z0, z1);
            float lse = m + logf(expf(z0 - m) + expf(z1 - m));
            float uu0 = ULf[2 * r];
            float uu1 = ULf[2 * r + 1];
            float q0v = (z0 - lse) + (-logf(-logf(uu0 + 1e-20f) + 1e-20f));
            float q1v = (z1 - lse) + (-logf(-logf(uu1 + 1e-20f) + 1e-20f));
            float mm = fmaxf(q0v, q1v);
            float e0 = expf(q0v - mm);
            float e1 = expf(q1v - mm);
            float s  = e0 + e1;
            float y0 = e0 / s;
            float y1 = e1 / s;
            bool  pick0 = (q0v >= q1v);             // argmax, first index wins ties
            float s0 = pick0 ? ((1.f - y0) + y0) : 0.f;
            float s1v = pick0 ? 0.f : ((1.f - y1) + y1);
            if (lane == 0) { SEL[cur][2 * r] = s0; SEL[cur][2 * r + 1] = s1v; }
        }
        __syncthreads();

        // ---- gated store: flat, 128B-aligned, full lines only ----
        f4* o = out + (size_t)tile * TILE_F4_OUT;
        #pragma unroll
        for (int k = 0; k < 4; k++) {
            const int j   = k * BDIM + tid;
            const int row = j / 150;
            const int rem = j - row * 150;
            const bool first = (rem < 75);
            f4 v = first ? L1[cur][row * 75 + rem] : L2[cur][row * 75 + rem - 75];
            float sc = SEL[cur][2 * row + (first ? 0 : 1)];
            __builtin_nontemporal_store(v * sc, o + j);
        }
        if (tid < TILE_F4_OUT - 4 * BDIM) {        // 176 threads
            const int j   = 4 * BDIM + tid;
            const int row = j / 150;
            const int rem = j - row * 150;
            const bool first = (rem < 75);
            f4 v = first ? L1[cur][row * 75 + rem] : L2[cur][row * 75 + rem - 75];
            float sc = SEL[cur][2 * row + (first ? 0 : 1)];
            __builtin_nontemporal_store(v * sc, o + j);
        }
        // no third barrier needed: iteration i+1's mid-barrier orders
        // iteration i's stores before iteration i+2 overwrites LDS[cur]

        tile += NBLK;
    }
}

extern "C" void kernel_launch(void* const* d_in, const int* in_sizes, int n_in,
                              void* d_out, int out_size, void* d_ws, size_t ws_size,
                              hipStream_t stream) {
    const f4* se1 = (const f4*)d_in[0];
    const f4* se2 = (const f4*)d_in[1];
    const float* W = (const float*)d_in[2];
    const float* b = (const float*)d_in[3];
    const f4* u4  = (const f4*)d_in[4];
    f4* out = (f4*)d_out;

    const int Brows = in_sizes[0] / 300;     // 131072
    const int ntiles = Brows / TROWS;        // 16384 (exact, = 16 * NBLK)

    taskselector_kernel<<<NBLK, BDIM, 0, stream>>>(se1, se2, W, b, u4, out, ntiles);
}